// Round 7
// baseline (1073.456 us; speedup 1.0000x reference)
//
#include <hip/hip_runtime.h>
#include <stdint.h>

constexpr int kN    = 100000;   // nodes
constexpr int kDOut = 128;      // output dim
constexpr int kDIn  = 256;      // input feature dim
constexpr int kNNZ  = 3200000;  // nnz for both X and A
constexpr float kInvKeep = (float)(1.0 / 0.9);

// ---------------- RNG (verified round 4: partitionable, bits = o0^o1) -----
__device__ __forceinline__ uint32_t rotl32(uint32_t v, int r) {
  return (v << r) | (v >> (32 - r));
}
__device__ __forceinline__ void threefry2x32(uint32_t k0, uint32_t k1,
                                             uint32_t x0, uint32_t x1,
                                             uint32_t& o0, uint32_t& o1) {
  const uint32_t ks0 = k0, ks1 = k1, ks2 = k0 ^ k1 ^ 0x1BD11BDAu;
  x0 += ks0; x1 += ks1;
#define TF_RND(r) { x0 += x1; x1 = rotl32(x1, (r)); x1 ^= x0; }
  TF_RND(13) TF_RND(15) TF_RND(26) TF_RND(6)
  x0 += ks1; x1 += ks2 + 1u;
  TF_RND(17) TF_RND(29) TF_RND(16) TF_RND(24)
  x0 += ks2; x1 += ks0 + 2u;
  TF_RND(13) TF_RND(15) TF_RND(26) TF_RND(6)
  x0 += ks0; x1 += ks1 + 3u;
  TF_RND(17) TF_RND(29) TF_RND(16) TF_RND(24)
  x0 += ks1; x1 += ks2 + 4u;
  TF_RND(13) TF_RND(15) TF_RND(26) TF_RND(6)
  x0 += ks2; x1 += ks0 + 5u;
#undef TF_RND
  o0 = x0; o1 = x1;
}
__device__ __forceinline__ float keep_mask(uint32_t i) {
  uint32_t o0, o1;
  threefry2x32(0u, 42u, 0u, i, o0, o1);
  uint32_t bits = o0 ^ o1;
  float u = __uint_as_float((bits >> 9) | 0x3f800000u) - 1.0f;
  return floorf(0.9f + u);
}

// ---------------- bf16 helpers (RTNE) --------------------------------------
__device__ __forceinline__ uint16_t f32_to_bf16(float f) {
  uint32_t u = __float_as_uint(f);
  u += 0x7fffu + ((u >> 16) & 1u);
  return (uint16_t)(u >> 16);
}
__device__ __forceinline__ float bf16lo_to_f32(uint32_t packed) {
  return __uint_as_float(packed << 16);
}
__device__ __forceinline__ float bf16hi_to_f32(uint32_t packed) {
  return __uint_as_float(packed & 0xffff0000u);
}

// ---------------- non-temporal load helpers ---------------------------------
__device__ __forceinline__ int      nt_i  (const int* p)      { return __builtin_nontemporal_load(p); }
__device__ __forceinline__ float    nt_f  (const float* p)    { return __builtin_nontemporal_load(p); }
__device__ __forceinline__ uint64_t nt_u64(const uint64_t* p) { return __builtin_nontemporal_load(p); }

// ---------------- CSR build: histogram -> scan -> scatter ------------------
template<bool DROPOUT>
__global__ void hist_kernel(const int* __restrict__ rows, int* __restrict__ cnt,
                            int nnz) {
  int e = blockIdx.x * blockDim.x + threadIdx.x;
  if (e >= nnz) return;
  int r = nt_i(rows + e);
  if (DROPOUT && keep_mask((uint32_t)e) == 0.0f) return;
  atomicAdd(&cnt[r], 1);
}

constexpr int kScanChunk = 2048;   // 256 threads x 8 elems
constexpr int kScanBlk   = (kN + kScanChunk - 1) / kScanChunk;  // 49

__global__ void scan1_kernel(const int* __restrict__ cnt, int* __restrict__ rowptr,
                             int* __restrict__ partials, int n) {
  __shared__ int sd[256];
  int b = blockIdx.x, t = threadIdx.x;
  int base = b * kScanChunk + t * 8;
  int v[8]; int s = 0;
  #pragma unroll
  for (int k = 0; k < 8; ++k) { int idx = base + k; v[k] = (idx < n) ? cnt[idx] : 0; s += v[k]; }
  sd[t] = s; __syncthreads();
  #pragma unroll
  for (int off = 1; off < 256; off <<= 1) {
    int x = (t >= off) ? sd[t - off] : 0;
    __syncthreads();
    sd[t] += x;
    __syncthreads();
  }
  if (t == 255) partials[b] = sd[255];
  int run = (t == 0) ? 0 : sd[t - 1];
  #pragma unroll
  for (int k = 0; k < 8; ++k) { int idx = base + k; if (idx < n) rowptr[idx] = run; run += v[k]; }
}

__global__ void scan2_kernel(int* __restrict__ partials, int* __restrict__ rowptr,
                             int nblk, int n) {
  __shared__ int sd[64];
  int t = threadIdx.x;
  sd[t] = (t < nblk) ? partials[t] : 0;
  __syncthreads();
  #pragma unroll
  for (int off = 1; off < 64; off <<= 1) {
    int x = (t >= off) ? sd[t - off] : 0;
    __syncthreads();
    sd[t] += x;
    __syncthreads();
  }
  if (t < nblk) partials[t] = (t == 0) ? 0 : sd[t - 1];
  if (t == 63) rowptr[n] = sd[63];
}

// finalize rowptr AND seed cur = rowptr (scatter bumps cur directly)
__global__ void scan3_kernel(int* __restrict__ rowptr, int* __restrict__ cur,
                             const int* __restrict__ partials, int n) {
  int i = blockIdx.x * blockDim.x + threadIdx.x;
  if (i < n) {
    int v = rowptr[i] + partials[i / kScanChunk];
    rowptr[i] = v;
    cur[i] = v;
  }
}

// scatter packed (col | val<<32) -> single 8B store per edge
template<bool DROPOUT>
__global__ void scatter_kernel(const int* __restrict__ rows, const int* __restrict__ cols,
                               const float* __restrict__ vals,
                               int* __restrict__ cur,
                               uint64_t* __restrict__ spack, int nnz) {
  int e = blockIdx.x * blockDim.x + threadIdx.x;
  if (e >= nnz) return;
  int r = nt_i(rows + e);
  int c = nt_i(cols + e);
  float v = nt_f(vals + e);
  if (DROPOUT) {
    if (keep_mask((uint32_t)e) == 0.0f) return;
    v *= kInvKeep;
  }
  int pos = atomicAdd(&cur[r], 1);
  spack[pos] = (uint64_t)(uint32_t)c | ((uint64_t)__float_as_uint(v) << 32);
}

// ---------------- W (f32, [kDIn][kDOut]) -> bf16 copy ----------------------
__global__ void wcvt_kernel(const float* __restrict__ W, uint16_t* __restrict__ Wb) {
  int i = blockIdx.x * blockDim.x + threadIdx.x;
  if (i < kDIn * kDOut) Wb[i] = f32_to_bf16(nt_f(W + i));
}

// ---------------- CSR SpMM, bf16 B-matrix ----------------------------------
// 4 rows per 256-thread block; 64 lanes/row; lane computes d=2*lane, 2*lane+1
// via one 4B bf16x2 gather per edge. spack is NT-read (streamed once).
template<bool OUT_BF16, bool RELU>
__global__ void spmm_csr_kernel(const int* __restrict__ rowptr,
                                const uint64_t* __restrict__ spack,
                                const uint16_t* __restrict__ B,  // bf16 [*, kDOut]
                                void* __restrict__ outv, int nrows) {
  int tid = threadIdx.x;
  int row = blockIdx.x * 4 + (tid >> 6);
  int lane = tid & 63;
  if (row >= nrows) return;
  int e = rowptr[row], e_end = rowptr[row + 1];
  float a0 = 0.0f, a1 = 0.0f;
  const int doff = lane * 2;
  for (; e + 1 < e_end; e += 2) {
    uint64_t p0 = nt_u64(spack + e);
    uint64_t p1 = nt_u64(spack + e + 1);
    uint32_t c0 = (uint32_t)p0, c1 = (uint32_t)p1;
    float v0 = __uint_as_float((uint32_t)(p0 >> 32));
    float v1 = __uint_as_float((uint32_t)(p1 >> 32));
    uint32_t g0 = *(const uint32_t*)(B + (size_t)c0 * kDOut + doff);
    uint32_t g1 = *(const uint32_t*)(B + (size_t)c1 * kDOut + doff);
    a0 += v0 * bf16lo_to_f32(g0);
    a1 += v0 * bf16hi_to_f32(g0);
    a0 += v1 * bf16lo_to_f32(g1);
    a1 += v1 * bf16hi_to_f32(g1);
  }
  if (e < e_end) {
    uint64_t p0 = nt_u64(spack + e);
    uint32_t c0 = (uint32_t)p0;
    float v0 = __uint_as_float((uint32_t)(p0 >> 32));
    uint32_t g0 = *(const uint32_t*)(B + (size_t)c0 * kDOut + doff);
    a0 += v0 * bf16lo_to_f32(g0);
    a1 += v0 * bf16hi_to_f32(g0);
  }
  if (RELU) { a0 = fmaxf(a0, 0.0f); a1 = fmaxf(a1, 0.0f); }
  if (OUT_BF16) {
    // hb is re-read by spmm2: normal (cached) store
    uint32_t packed = (uint32_t)f32_to_bf16(a0) | ((uint32_t)f32_to_bf16(a1) << 16);
    ((uint32_t*)outv)[(size_t)row * (kDOut / 2) + lane] = packed;
  } else {
    // final out: never re-read -> NT store, keep L2 for h gathers
    union { float2 f; uint64_t u; } cv;
    cv.f.x = a0; cv.f.y = a1;
    __builtin_nontemporal_store(cv.u, (uint64_t*)outv + (size_t)row * (kDOut / 2) + lane);
  }
}

// ---------------------------------------------------------------------------
extern "C" void kernel_launch(void* const* d_in, const int* in_sizes, int n_in,
                              void* d_out, int out_size, void* d_ws, size_t ws_size,
                              hipStream_t stream) {
  const int*   x_rows   = (const int*)d_in[0];
  const int*   x_cols   = (const int*)d_in[1];
  const float* x_vals   = (const float*)d_in[2];
  const int*   adj_rows = (const int*)d_in[3];
  const int*   adj_cols = (const int*)d_in[4];
  const float* adj_vals = (const float*)d_in[5];
  const float* W        = (const float*)d_in[6];
  float* out = (float*)d_out;

  // workspace layout (256B-aligned chunks)
  size_t off = 0;
  auto take = [&](size_t bytes) -> char* {
    char* p = (char*)d_ws + off;
    off += (bytes + 255) & ~(size_t)255;
    return p;
  };
  uint16_t* hb     = (uint16_t*)take((size_t)kN * kDOut * 2);   // 25.6 MB (bf16 h)
  uint16_t* Wb     = (uint16_t*)take((size_t)kDIn * kDOut * 2); // 64 KB
  int*      rowptr = (int*)take((size_t)(kN + 1) * 4);          // 400 KB
  int*      cur    = (int*)take((size_t)kN * 4);                // 400 KB
  uint64_t* spack  = (uint64_t*)take((size_t)kNNZ * 8);         // 25.6 MB
  int*      partials = (int*)take(64 * 4);
  const size_t needed = off;                                    // ~52.3 MB
  if (ws_size < needed) return;

  const int histBlocks = (kNNZ + 255) / 256;
  const int spmmBlocks = (kN + 3) / 4;

  wcvt_kernel<<<(kDIn * kDOut + 255) / 256, 256, 0, stream>>>(W, Wb);

  // ---------- X: CSR build (dropout folded) + spmm1 -> hb ----------
  hipMemsetAsync(cur, 0, (size_t)kN * 4, stream);
  hist_kernel<true><<<histBlocks, 256, 0, stream>>>(x_rows, cur, kNNZ);
  scan1_kernel<<<kScanBlk, 256, 0, stream>>>(cur, rowptr, partials, kN);
  scan2_kernel<<<1, 64, 0, stream>>>(partials, rowptr, kScanBlk, kN);
  scan3_kernel<<<(kN + 255) / 256, 256, 0, stream>>>(rowptr, cur, partials, kN);
  scatter_kernel<true><<<histBlocks, 256, 0, stream>>>(
      x_rows, x_cols, x_vals, cur, spack, kNNZ);
  spmm_csr_kernel<true, false><<<spmmBlocks, 256, 0, stream>>>(
      rowptr, spack, Wb, hb, kN);

  // ---------- adj: CSR build (reuse buffers) + spmm2(+relu) -> out ----------
  hipMemsetAsync(cur, 0, (size_t)kN * 4, stream);
  hist_kernel<false><<<histBlocks, 256, 0, stream>>>(adj_rows, cur, kNNZ);
  scan1_kernel<<<kScanBlk, 256, 0, stream>>>(cur, rowptr, partials, kN);
  scan2_kernel<<<1, 64, 0, stream>>>(partials, rowptr, kScanBlk, kN);
  scan3_kernel<<<(kN + 255) / 256, 256, 0, stream>>>(rowptr, cur, partials, kN);
  scatter_kernel<false><<<histBlocks, 256, 0, stream>>>(
      adj_rows, adj_cols, adj_vals, cur, spack, kNNZ);
  spmm_csr_kernel<false, true><<<spmmBlocks, 256, 0, stream>>>(
      rowptr, spack, hb, out, kN);
}